// Round 2
// baseline (211.890 us; speedup 1.0000x reference)
//
#include <hip/hip_runtime.h>
#include <math.h>

#define NSAMP 256

__global__ __launch_bounds__(256) void nerf_fused(
    const float* __restrict__ rays_o, const float* __restrict__ rays_d,
    const float* __restrict__ G1, const float* __restrict__ Fg,
    const float* __restrict__ Wd1, const float* __restrict__ bd1,
    const float* __restrict__ Wd2, const float* __restrict__ bd2,
    const float* __restrict__ Wc1, const float* __restrict__ bc1,
    const float* __restrict__ Wc2, const float* __restrict__ bc2,
    float* __restrict__ out)
{
    const float RADIUS = 1.3f;
    const float STEP = 0.0176f;

    const int b    = blockIdx.x;
    const int tid  = threadIdx.x;
    const int lane = tid & 63;
    const int wv   = tid >> 6;

    __shared__ float s_wtot[4];
    __shared__ float s_red[4][4];

    // ---- ray setup (redundant per thread; 6 broadcast loads) ----
    const float ox = rays_o[b*3+0], oy = rays_o[b*3+1], oz = rays_o[b*3+2];
    const float rdx = rays_d[b*3+0], rdy = rays_d[b*3+1], rdz = rays_d[b*3+2];
    const float rn  = sqrtf(rdx*rdx + rdy*rdy + rdz*rdz);
    const float dxn = rdx/rn, dyn = rdy/rn, dzn = rdz/rn;

    // ---- cube intersection ----
    float sd, inv, t1, t2, tmin, tmax;
    sd = (fabsf(dxn) < 1e-9f) ? 1e-9f : dxn; inv = 1.0f/sd;
    t1 = (-RADIUS - ox)*inv; t2 = (RADIUS - ox)*inv;
    tmin = fminf(t1,t2); tmax = fmaxf(t1,t2);
    sd = (fabsf(dyn) < 1e-9f) ? 1e-9f : dyn; inv = 1.0f/sd;
    t1 = (-RADIUS - oy)*inv; t2 = (RADIUS - oy)*inv;
    tmin = fmaxf(tmin, fminf(t1,t2)); tmax = fminf(tmax, fmaxf(t1,t2));
    sd = (fabsf(dzn) < 1e-9f) ? 1e-9f : dzn; inv = 1.0f/sd;
    t1 = (-RADIUS - oz)*inv; t2 = (RADIUS - oz)*inv;
    tmin = fmaxf(tmin, fminf(t1,t2)); tmax = fminf(tmax, fmaxf(t1,t2));

    const float tnear = fmaxf(tmin, 0.0f);
    const bool  hit   = tmax > tnear;
    const float t     = tnear + STEP * (float)tid;
    const bool  mask  = (t < tmax) && hit;

    // ---- sample position, normalized to [-1,1] ----
    const float invR = 1.0f / RADIUS;
    const float px = (ox + t*dxn) * invR;
    const float py = (oy + t*dyn) * invR;
    const float pz = (oz + t*dzn) * invR;

    // ---- trilinear G1 (C=3, 128^3), border-clamped, align_corners ----
    float cox = fminf(fmaxf((px+1.0f)*0.5f*127.0f, 0.0f), 127.0f);
    float coy = fminf(fmaxf((py+1.0f)*0.5f*127.0f, 0.0f), 127.0f);
    float coz = fminf(fmaxf((pz+1.0f)*0.5f*127.0f, 0.0f), 127.0f);
    int x0 = (int)floorf(cox); float fx = cox - (float)x0; int x1 = min(x0+1, 127);
    int y0 = (int)floorf(coy); float fy = coy - (float)y0; int y1 = min(y0+1, 127);
    int z0 = (int)floorf(coz); float fz = coz - (float)z0; int z1 = min(z0+1, 127);

    {
        // corner weights (shared across channels)
        const float wx0 = 1.0f-fx, wx1 = fx;
        const float wy0 = 1.0f-fy, wy1 = fy;
        const float wz0 = 1.0f-fz, wz1 = fz;
        const float w000 = wx0*wy0*wz0, w100 = wx1*wy0*wz0;
        const float w010 = wx0*wy1*wz0, w110 = wx1*wy1*wz0;
        const float w001 = wx0*wy0*wz1, w101 = wx1*wy0*wz1;
        const float w011 = wx0*wy1*wz1, w111 = wx1*wy1*wz1;
        const int i000 = (z0*128 + y0)*128 + x0;
        const int dxo = x1 - x0;
        const int dyo = (y1 - y0)*128;
        const int dzo = (z1 - z0)*16384;
        const int i100 = i000 + dxo,       i010 = i000 + dyo;
        const int i110 = i000 + dyo + dxo, i001 = i000 + dzo;
        const int i101 = i000 + dzo + dxo, i011 = i000 + dzo + dyo;
        const int i111 = i000 + dzo + dyo + dxo;

        float g[3];
        #pragma unroll
        for (int c = 0; c < 3; ++c) {
            const float* gp = G1 + (size_t)c * 2097152;
            g[c] = w000*gp[i000] + w100*gp[i100] + w010*gp[i010] + w110*gp[i110]
                 + w001*gp[i001] + w101*gp[i101] + w011*gp[i011] + w111*gp[i111];
        }

        // ---- trilinear F (C=32, 32^3) at coords g ----
        cox = fminf(fmaxf((g[0]+1.0f)*0.5f*31.0f, 0.0f), 31.0f);
        coy = fminf(fmaxf((g[1]+1.0f)*0.5f*31.0f, 0.0f), 31.0f);
        coz = fminf(fmaxf((g[2]+1.0f)*0.5f*31.0f, 0.0f), 31.0f);
        x0 = (int)floorf(cox); fx = cox - (float)x0; x1 = min(x0+1, 31);
        y0 = (int)floorf(coy); fy = coy - (float)y0; y1 = min(y0+1, 31);
        z0 = (int)floorf(coz); fz = coz - (float)z0; z1 = min(z0+1, 31);
    }

    float feats[32];
    {
        const float wx0 = 1.0f-fx, wx1 = fx;
        const float wy0 = 1.0f-fy, wy1 = fy;
        const float wz0 = 1.0f-fz, wz1 = fz;
        const float w000 = wx0*wy0*wz0, w100 = wx1*wy0*wz0;
        const float w010 = wx0*wy1*wz0, w110 = wx1*wy1*wz0;
        const float w001 = wx0*wy0*wz1, w101 = wx1*wy0*wz1;
        const float w011 = wx0*wy1*wz1, w111 = wx1*wy1*wz1;
        const int j000 = (z0*32 + y0)*32 + x0;
        const int dxo = x1 - x0;
        const int dyo = (y1 - y0)*32;
        const int dzo = (z1 - z0)*1024;
        const int j100 = j000 + dxo,       j010 = j000 + dyo;
        const int j110 = j000 + dyo + dxo, j001 = j000 + dzo;
        const int j101 = j000 + dzo + dxo, j011 = j000 + dzo + dyo;
        const int j111 = j000 + dzo + dyo + dxo;

        #pragma unroll 4
        for (int c = 0; c < 32; ++c) {
            const float* fp = Fg + (size_t)c * 32768;
            feats[c] = w000*fp[j000] + w100*fp[j100] + w010*fp[j010] + w110*fp[j110]
                     + w001*fp[j001] + w101*fp[j101] + w011*fp[j011] + w111*fp[j111];
        }
    }

    // ---- density MLP: relu(feats @ Wd1 + bd1) @ Wd2 + bd2 ----
    float sigma = bd2[0];
    for (int j0 = 0; j0 < 64; j0 += 8) {
        float a[8];
        #pragma unroll
        for (int jj = 0; jj < 8; ++jj) a[jj] = bd1[j0+jj];
        #pragma unroll
        for (int k = 0; k < 32; ++k) {
            const float fv = feats[k];
            #pragma unroll
            for (int jj = 0; jj < 8; ++jj) a[jj] += fv * Wd1[k*64 + j0 + jj];
        }
        #pragma unroll
        for (int jj = 0; jj < 8; ++jj) sigma += fmaxf(a[jj], 0.0f) * Wd2[j0+jj];
    }

    // ---- color MLP: relu([feats, dirn] @ Wc1 + bc1) @ Wc2 + bc2, sigmoid ----
    float cr = 0.0f, cg = 0.0f, cb = 0.0f;
    for (int j0 = 0; j0 < 64; j0 += 8) {
        float a[8];
        #pragma unroll
        for (int jj = 0; jj < 8; ++jj)
            a[jj] = bc1[j0+jj] + dxn*Wc1[32*64 + j0 + jj]
                               + dyn*Wc1[33*64 + j0 + jj]
                               + dzn*Wc1[34*64 + j0 + jj];
        #pragma unroll
        for (int k = 0; k < 32; ++k) {
            const float fv = feats[k];
            #pragma unroll
            for (int jj = 0; jj < 8; ++jj) a[jj] += fv * Wc1[k*64 + j0 + jj];
        }
        #pragma unroll
        for (int jj = 0; jj < 8; ++jj) {
            const float hc = fmaxf(a[jj], 0.0f);
            cr += hc * Wc2[(j0+jj)*3 + 0];
            cg += hc * Wc2[(j0+jj)*3 + 1];
            cb += hc * Wc2[(j0+jj)*3 + 2];
        }
    }
    cr += bc2[0]; cg += bc2[1]; cb += bc2[2];
    float rr = 1.0f/(1.0f + expf(-cr));
    float rg = 1.0f/(1.0f + expf(-cg));
    float rb = 1.0f/(1.0f + expf(-cb));

    // ---- masking ----
    const float sig_m = mask ? sigma : 0.0f;
    rr = mask ? rr : 0.0f;
    rg = mask ? rg : 0.0f;
    rb = mask ? rb : 0.0f;

    // ---- alpha, exclusive product scan (T_excl), weights ----
    const float alpha = 1.0f - expf(-fmaxf(sig_m, 0.0f) * STEP);
    float p = 1.0f - alpha + 1e-10f;

    // wave-level inclusive product scan
    float scan = p;
    #pragma unroll
    for (int off = 1; off < 64; off <<= 1) {
        const float n = __shfl_up(scan, off, 64);
        if (lane >= off) scan *= n;
    }
    if (lane == 63) s_wtot[wv] = scan;   // wave total (inclusive over 64)
    __syncthreads();

    float pre = 1.0f;
    for (int q = 0; q < 4; ++q) if (q < wv) pre *= s_wtot[q];
    float excl = __shfl_up(scan, 1, 64);
    if (lane == 0) excl = 1.0f;
    const float Texcl = pre * excl;

    const float w = alpha * Texcl;
    float sw  = w;
    float swr = w * rr, swg = w * rg, swb = w * rb;

    // ---- block reduction ----
    #pragma unroll
    for (int off = 32; off > 0; off >>= 1) {
        sw  += __shfl_down(sw,  off, 64);
        swr += __shfl_down(swr, off, 64);
        swg += __shfl_down(swg, off, 64);
        swb += __shfl_down(swb, off, 64);
    }
    if (lane == 0) {
        s_red[wv][0] = sw;  s_red[wv][1] = swr;
        s_red[wv][2] = swg; s_red[wv][3] = swb;
    }
    __syncthreads();
    if (tid == 0) {
        float W = 0.0f, R = 0.0f, Gc = 0.0f, Bc = 0.0f;
        #pragma unroll
        for (int q = 0; q < 4; ++q) {
            W  += s_red[q][0]; R  += s_red[q][1];
            Gc += s_red[q][2]; Bc += s_red[q][3];
        }
        const float bg = 1.0f - W;
        out[b*3+0] = R  + bg;
        out[b*3+1] = Gc + bg;
        out[b*3+2] = Bc + bg;
    }
}

extern "C" void kernel_launch(void* const* d_in, const int* in_sizes, int n_in,
                              void* d_out, int out_size, void* d_ws, size_t ws_size,
                              hipStream_t stream) {
    const float* rays_o = (const float*)d_in[0];
    const float* rays_d = (const float*)d_in[1];
    const float* G1     = (const float*)d_in[2];
    const float* Fg     = (const float*)d_in[3];
    const float* Wd1    = (const float*)d_in[4];
    const float* bd1    = (const float*)d_in[5];
    const float* Wd2    = (const float*)d_in[6];
    const float* bd2    = (const float*)d_in[7];
    const float* Wc1    = (const float*)d_in[8];
    const float* bc1    = (const float*)d_in[9];
    const float* Wc2    = (const float*)d_in[10];
    const float* bc2    = (const float*)d_in[11];
    float* out = (float*)d_out;

    const int B = in_sizes[0] / 3;   // 2048 rays
    nerf_fused<<<dim3(B), dim3(NSAMP), 0, stream>>>(
        rays_o, rays_d, G1, Fg, Wd1, bd1, Wd2, bd2, Wc1, bc1, Wc2, bc2, out);
}